// Round 4
// baseline (9601.047 us; speedup 1.0000x reference)
//
#include <hip/hip_runtime.h>

// LiquidLayer: h_t = h + DT*(-h/tau + tanh(xW_t + h U^T + b)), T=1024 steps.
// Out = [h_final (32x1024) | states (32x1024x1024)] f32.
// Phase 1: xW GEMM (f32, tiled) written in-place into states region.
// Phase 2: ONE persistent kernel, 32 WGs x 4 waves (256 thr), 1 WG/CU.
//          WG = (mg 0..1) x (jw 0..15): owns 16 batch rows x 64 cols.
//          Cross-WG exchange of bf16 h through the coherent point using
//          SYSTEM-scope relaxed atomics (sc0+sc1 bypass L1 + non-coherent
//          per-XCD L2). Barrier = 16-entry per-group FLAG ARRAY (plain
//          monotonic stores, no atomic RMW; consumers read all 16 flags in
//          one 64-lane load + __all). Tight poll (no s_sleep), 1s realtime
//          watchdog so a protocol failure can never hang the container.

#define DT 0.1f
#define BB 32
#define TT 1024
#define II 512
#define HH 1024

typedef __attribute__((ext_vector_type(4))) float f32x4;
typedef __attribute__((ext_vector_type(8))) short s16x8;

__device__ __forceinline__ unsigned short f2bf(float f) {
  unsigned int u = __builtin_bit_cast(unsigned int, f);
  u += 0x7fffu + ((u >> 16) & 1u);  // RNE
  return (unsigned short)(u >> 16);
}

// tanh via HW exp2 + rcp: tanh(x) = 1 - 2/(e^{2x}+1). |err| ~1e-6 << bf16
// h quantization (2e-3). ~8 instr vs ~40 for ocml tanhf.
__device__ __forceinline__ float fast_tanh(float x) {
  float z = __expf(2.0f * x);
  return 1.0f - 2.0f * __builtin_amdgcn_rcpf(z + 1.0f);
}

// ---------------- U f32 -> bf16 (runs every call; ws is re-poisoned) --------
__global__ __launch_bounds__(256) void cvt_u_kernel(const float* __restrict__ U,
                                                    unsigned short* __restrict__ Ub) {
  int i4 = (blockIdx.x * 256 + threadIdx.x) * 4;
  float4 v = *(const float4*)(U + i4);
  ushort4 o;
  o.x = f2bf(v.x); o.y = f2bf(v.y); o.z = f2bf(v.z); o.w = f2bf(v.w);
  *(ushort4*)(Ub + i4) = o;
}

// ---------------- Phase 1: xW[m][n] = sum_k x[m][k] * W[n][k] (f32) ---------
// M=32768, N=1024, K=512. Block tile 128x128, 256 threads, 8x8 per thread.
#define P1_LDK 36  // LDS row stride (words): pad 32->36; even, 16B-aligned rows

__global__ __launch_bounds__(256) void xw_gemm(const float* __restrict__ x,
                                               const float* __restrict__ W,
                                               float* __restrict__ out) {
  __shared__ __align__(16) float Xs[128 * P1_LDK];
  __shared__ __align__(16) float Ws_s[128 * P1_LDK];
  const int tid = threadIdx.x;
  const int m0 = blockIdx.y * 128;
  const int n0 = blockIdx.x * 128;
  const int ty = tid >> 4;       // 0..15
  const int tx = tid & 15;       // 0..15
  const int lrow = tid >> 3;     // loader: 0..31
  const int lf = tid & 7;        // loader: float4 column 0..7

  float acc[8][8];
#pragma unroll
  for (int i = 0; i < 8; ++i)
#pragma unroll
    for (int j = 0; j < 8; ++j) acc[i][j] = 0.0f;

  for (int kk = 0; kk < II; kk += 32) {
#pragma unroll
    for (int p = 0; p < 4; ++p) {
      int r = lrow + 32 * p;
      float4 vx = *(const float4*)&x[(m0 + r) * II + kk + 4 * lf];
      *(float4*)&Xs[r * P1_LDK + 4 * lf] = vx;
      float4 vw = *(const float4*)&W[(n0 + r) * II + kk + 4 * lf];
      *(float4*)&Ws_s[r * P1_LDK + 4 * lf] = vw;
    }
    __syncthreads();
#pragma unroll
    for (int kq = 0; kq < 32; kq += 4) {
      float4 a[8], b[8];
#pragma unroll
      for (int i = 0; i < 4; ++i) {
        a[i]     = *(const float4*)&Xs[(ty * 4 + i) * P1_LDK + kq];
        a[i + 4] = *(const float4*)&Xs[(ty * 4 + i + 64) * P1_LDK + kq];
      }
#pragma unroll
      for (int j = 0; j < 8; ++j)
        b[j] = *(const float4*)&Ws_s[(tx + 16 * j) * P1_LDK + kq];
#pragma unroll
      for (int i = 0; i < 8; ++i)
#pragma unroll
        for (int j = 0; j < 8; ++j) {
          acc[i][j] += a[i].x * b[j].x;
          acc[i][j] += a[i].y * b[j].y;
          acc[i][j] += a[i].z * b[j].z;
          acc[i][j] += a[i].w * b[j].w;
        }
    }
    __syncthreads();
  }
#pragma unroll
  for (int i = 0; i < 8; ++i) {
    int m = m0 + ty * 4 + (i < 4 ? i : 64 + i - 4);
#pragma unroll
    for (int j = 0; j < 8; ++j)
      out[m * HH + n0 + tx + 16 * j] = acc[i][j];
  }
}

// ---------------- Phase 2: persistent scan ----------------------------------
// 32 WGs x 256 threads (4 waves), 1 WG/CU. WG (mg, jw): batches mg*16..+16,
// cols jw*64..+64; wave w owns cols jw*64 + w*16 .. +16. The two mg halves
// are fully independent (disjoint flags / h rows / states rows).
//
// Protocol (NO cache-maintenance ops, NO atomic RMW):
//  - hbuf + flags touched ONLY via SYSTEM-scope relaxed atomics (bypass
//    L1/L2, served at the coherent point) => never stale anywhere.
//  - producer: h stores (sys) -> per-wave s_waitcnt vmcnt(0) ->
//    __syncthreads -> thread0 stores flag[jw] = t+1.
//  - consumer: one 64-lane load of the 16 flags, __all(f >= t) ->
//    sched_barrier -> h loads.
//  - states / hf: lane-private or kernel-final -> normal cached accesses,
//    issued AFTER the flag store (off the cross-WG critical path).
//  - watchdog: 1s deadline via s_memrealtime (checked every 64 polls; a
//    stuck protocol exits fast with a wrong answer, never a hung container).
__global__ __launch_bounds__(256, 1) void liquid_scan(
    const unsigned short* __restrict__ Ub,   // U bf16 [1024][1024]
    unsigned short* hbuf,                    // bf16 [2][32][1024] (exchange)
    int* arrivals,                           // [2][16] flags, 128 B apart
    float* __restrict__ hf,                  // h_final f32 [32][1024]
    float* __restrict__ states,              // [32][1024][1024]; holds xW at t
    const float* __restrict__ bias,
    const float* __restrict__ tau) {
  const int tid = threadIdx.x;
  const int l = tid & 63;            // lane
  const int w = tid >> 6;            // wave 0..3
  const int wg = blockIdx.x;
  const int mg = wg >> 4;            // 0..1
  const int jw = wg & 15;            // 0..15
  const int n = l & 15;              // MFMA col
  const int q = l >> 4;              // 0..3
  const int j = jw * 64 + w * 16 + n;  // this lane's output column
  const int arow = mg * 16 + n;        // A-fragment h row

  const unsigned long long deadline =
      __builtin_amdgcn_s_memrealtime() + 100000000ULL;  // +1 s @ 100 MHz

  // B fragments: lane holds B[k=q*8+i][n] = U[j][kc*32 + q*8 + i], 16 B each.
  s16x8 ufrag[32];
#pragma unroll
  for (int kc = 0; kc < 32; ++kc)
    ufrag[kc] = *(const s16x8*)(Ub + (size_t)j * HH + kc * 32 + q * 8);

  const float bj = bias[j];
  const float invt = 1.0f / tau[j];
  int* const myflags = arrivals + mg * 32;   // groups 128 B apart

  // h f32 register-resident: lane owns rows b = mg*16 + q*4 + r, col j.
  float hold[4] = {0.f, 0.f, 0.f, 0.f};
  float xw[4];
#pragma unroll
  for (int r = 0; r < 4; ++r)
    xw[r] = states[((size_t)(mg * 16 + q * 4 + r) * TT + 0) * HH + j];

  bool dead = false;
  for (int t = 0; t < TT; ++t) {
    const unsigned short* hin = hbuf + (size_t)(t & 1) * (BB * HH);
    unsigned short* hout = hbuf + (size_t)((t + 1) & 1) * (BB * HH);

    // prefetch next step's xw EARLY (lane-private; latency hides under the
    // barrier wait).
    const int tn = (t + 1 < TT) ? t + 1 : TT - 1;
    float xwn[4];
#pragma unroll
    for (int r = 0; r < 4; ++r)
      xwn[r] = states[((size_t)(mg * 16 + q * 4 + r) * TT + tn) * HH + j];

    if (t > 0) {
      // all 16 WGs of my group finished step t-1: flag[w'] >= t for all w'.
      int iter = 0;
      for (;;) {
        int f = __hip_atomic_load(&myflags[l & 15], __ATOMIC_RELAXED,
                                  __HIP_MEMORY_SCOPE_SYSTEM);
        if (__all(f >= t)) break;
        if (((++iter) & 63) == 0 &&
            __builtin_amdgcn_s_memrealtime() > deadline) { dead = true; break; }
      }
      if (dead) break;
      __builtin_amdgcn_sched_barrier(0);
    }

    // A fragments from the coherent point (8B system-scope loads):
    // lane holds A[m=l&15][k=q*8+i] = h[arow][kc*32 + q*8 + i].
    const unsigned long long* hrow =
        (const unsigned long long*)(hin + (size_t)arow * HH);
    s16x8 af[32];
#pragma unroll
    for (int kc = 0; kc < 32; ++kc) {
      unsigned long long lo = __hip_atomic_load(
          hrow + kc * 8 + q * 2, __ATOMIC_RELAXED, __HIP_MEMORY_SCOPE_SYSTEM);
      unsigned long long hi = __hip_atomic_load(
          hrow + kc * 8 + q * 2 + 1, __ATOMIC_RELAXED, __HIP_MEMORY_SCOPE_SYSTEM);
      union { unsigned long long u[2]; s16x8 v; } c;
      c.u[0] = lo; c.u[1] = hi;
      af[kc] = c.v;
    }

    // 4 accumulator chains to break MFMA latency serialization.
    f32x4 a0 = {0.f, 0.f, 0.f, 0.f}, a1 = {0.f, 0.f, 0.f, 0.f};
    f32x4 a2 = {0.f, 0.f, 0.f, 0.f}, a3 = {0.f, 0.f, 0.f, 0.f};
#pragma unroll
    for (int kc = 0; kc < 32; kc += 4) {
      a0 = __builtin_amdgcn_mfma_f32_16x16x32_bf16(af[kc + 0], ufrag[kc + 0], a0, 0, 0, 0);
      a1 = __builtin_amdgcn_mfma_f32_16x16x32_bf16(af[kc + 1], ufrag[kc + 1], a1, 0, 0, 0);
      a2 = __builtin_amdgcn_mfma_f32_16x16x32_bf16(af[kc + 2], ufrag[kc + 2], a2, 0, 0, 0);
      a3 = __builtin_amdgcn_mfma_f32_16x16x32_bf16(af[kc + 3], ufrag[kc + 3], a3, 0, 0, 0);
    }
    f32x4 acc = (a0 + a1) + (a2 + a3);

    // epilogue: D[row=q*4+r][col=n] -> batch b = mg*16+q*4+r, col j.
    float hn[4];
#pragma unroll
    for (int r = 0; r < 4; ++r) {
      const int b = mg * 16 + q * 4 + r;
      float pre = xw[r] + acc[r] + bj;
      float act = fast_tanh(pre);
      float hnew = hold[r] + DT * (act - invt * hold[r]);
      hold[r] = hnew;
      hn[r] = hnew;
      __hip_atomic_store(hout + b * HH + j, f2bf(hnew), __ATOMIC_RELAXED,
                         __HIP_MEMORY_SCOPE_SYSTEM);
      xw[r] = xwn[r];
    }

    // publish: each wave drains its h-stores, WG-barrier, then thread 0
    // stores the WG's flag (plain monotonic store -- no RMW serialization).
    asm volatile("s_waitcnt vmcnt(0)" ::: "memory");
    __syncthreads();
    if (tid == 0)
      __hip_atomic_store(&myflags[jw], t + 1, __ATOMIC_RELAXED,
                         __HIP_MEMORY_SCOPE_SYSTEM);

    // states stores: lane-private, read by nobody else -> normal cached
    // stores AFTER the flag store (off the cross-WG critical path).
#pragma unroll
    for (int r = 0; r < 4; ++r) {
      const int b = mg * 16 + q * 4 + r;
      states[((size_t)b * TT + t) * HH + j] = hn[r];
    }
  }

  // h_final
#pragma unroll
  for (int r = 0; r < 4; ++r)
    hf[(mg * 16 + q * 4 + r) * HH + j] = hold[r];
}

// ---------------------------------------------------------------------------
extern "C" void kernel_launch(void* const* d_in, const int* in_sizes, int n_in,
                              void* d_out, int out_size, void* d_ws, size_t ws_size,
                              hipStream_t stream) {
  const float* x    = (const float*)d_in[0];
  const float* W    = (const float*)d_in[1];
  const float* U    = (const float*)d_in[2];
  const float* bias = (const float*)d_in[3];
  const float* tau  = (const float*)d_in[4];

  float* out = (float*)d_out;
  float* hf = out;                         // [32][1024] -> h_final
  float* states = out + BB * HH;           // [32][1024][1024]

  unsigned short* Ub = (unsigned short*)d_ws;            // 2 MB
  unsigned short* hbuf = Ub + (size_t)HH * HH;           // 128 KB (2 buffers)
  int* arrivals = (int*)(hbuf + 2 * BB * HH);            // 256 B

  // init exchange buffers + flags (ws is re-poisoned before every call)
  hipMemsetAsync(hbuf, 0,
                 2 * BB * HH * sizeof(unsigned short) + 64 * sizeof(int),
                 stream);

  cvt_u_kernel<<<(HH * HH) / (256 * 4), 256, 0, stream>>>(U, Ub);

  // Phase 1: xW into the states region (overwritten in-place by the scan).
  xw_gemm<<<dim3(HH / 128, (BB * TT) / 128), 256, 0, stream>>>(x, W, states);

  // Phase 2: single persistent kernel; 32 WGs x 256 thr (1 WG/CU).
  liquid_scan<<<32, 256, 0, stream>>>(Ub, hbuf, arrivals, hf, states, bias, tau);
}

// Round 6
// 8532.877 us; speedup vs baseline: 1.1252x; 1.1252x over previous
//
#include <hip/hip_runtime.h>

// LiquidLayer: h_t = h + DT*(-h/tau + tanh(xW_t + h U^T + b)), T=1024 steps.
// Out = [h_final (32x1024) | states (32x1024x1024)] f32.
// Phase 1: xW GEMM (f32, tiled) written in-place into states region.
// Phase 2: ONE persistent kernel, 128 WGs x 1 wave (R3 structure; R4's 4-wave
//          WGs regressed 2x via per-CU uncached-traffic concentration).
//          Cross-WG exchange of bf16 h through the coherent point using
//          SYSTEM-scope relaxed atomics (sc0+sc1 bypass L1 + non-coherent
//          per-XCD L2); NO cache-maintenance ops, NO atomic RMW.
//          Barrier = 64-entry per-group flag array (plain monotonic stores).
//          Consumer polls flags[l] once per iteration, __ballot(f>=t), and
//          consumes the MFMA work in 4 chunks of 16 producers as their bits
//          arrive -- early chunks' loads/MFMAs hide under the wait for the
//          slowest producers. 1s per-iteration realtime watchdog (R3-proven)
//          so a protocol failure can never hang the container.

#define DT 0.1f
#define BB 32
#define TT 1024
#define II 512
#define HH 1024

typedef __attribute__((ext_vector_type(4))) float f32x4;
typedef __attribute__((ext_vector_type(8))) short s16x8;

__device__ __forceinline__ unsigned short f2bf(float f) {
  unsigned int u = __builtin_bit_cast(unsigned int, f);
  u += 0x7fffu + ((u >> 16) & 1u);  // RNE
  return (unsigned short)(u >> 16);
}

// tanh via HW exp2 + rcp: tanh(x) = 1 - 2/(e^{2x}+1). |err| ~1e-6 << bf16
// h quantization (2e-3). ~8 instr vs ~40 for ocml tanhf.
__device__ __forceinline__ float fast_tanh(float x) {
  float z = __expf(2.0f * x);
  return 1.0f - 2.0f * __builtin_amdgcn_rcpf(z + 1.0f);
}

// ---------------- U f32 -> bf16 (runs every call; ws is re-poisoned) --------
__global__ __launch_bounds__(256) void cvt_u_kernel(const float* __restrict__ U,
                                                    unsigned short* __restrict__ Ub) {
  int i4 = (blockIdx.x * 256 + threadIdx.x) * 4;
  float4 v = *(const float4*)(U + i4);
  ushort4 o;
  o.x = f2bf(v.x); o.y = f2bf(v.y); o.z = f2bf(v.z); o.w = f2bf(v.w);
  *(ushort4*)(Ub + i4) = o;
}

// ---------------- Phase 1: xW[m][n] = sum_k x[m][k] * W[n][k] (f32) ---------
// M=32768, N=1024, K=512. Block tile 128x128, 256 threads, 8x8 per thread.
#define P1_LDK 36  // LDS row stride (words): pad 32->36; even, 16B-aligned rows

__global__ __launch_bounds__(256) void xw_gemm(const float* __restrict__ x,
                                               const float* __restrict__ W,
                                               float* __restrict__ out) {
  __shared__ __align__(16) float Xs[128 * P1_LDK];
  __shared__ __align__(16) float Ws_s[128 * P1_LDK];
  const int tid = threadIdx.x;
  const int m0 = blockIdx.y * 128;
  const int n0 = blockIdx.x * 128;
  const int ty = tid >> 4;       // 0..15
  const int tx = tid & 15;       // 0..15
  const int lrow = tid >> 3;     // loader: 0..31
  const int lf = tid & 7;        // loader: float4 column 0..7

  float acc[8][8];
#pragma unroll
  for (int i = 0; i < 8; ++i)
#pragma unroll
    for (int j = 0; j < 8; ++j) acc[i][j] = 0.0f;

  for (int kk = 0; kk < II; kk += 32) {
#pragma unroll
    for (int p = 0; p < 4; ++p) {
      int r = lrow + 32 * p;
      float4 vx = *(const float4*)&x[(m0 + r) * II + kk + 4 * lf];
      *(float4*)&Xs[r * P1_LDK + 4 * lf] = vx;
      float4 vw = *(const float4*)&W[(n0 + r) * II + kk + 4 * lf];
      *(float4*)&Ws_s[r * P1_LDK + 4 * lf] = vw;
    }
    __syncthreads();
#pragma unroll
    for (int kq = 0; kq < 32; kq += 4) {
      float4 a[8], b[8];
#pragma unroll
      for (int i = 0; i < 4; ++i) {
        a[i]     = *(const float4*)&Xs[(ty * 4 + i) * P1_LDK + kq];
        a[i + 4] = *(const float4*)&Xs[(ty * 4 + i + 64) * P1_LDK + kq];
      }
#pragma unroll
      for (int j = 0; j < 8; ++j)
        b[j] = *(const float4*)&Ws_s[(tx + 16 * j) * P1_LDK + kq];
#pragma unroll
      for (int i = 0; i < 8; ++i)
#pragma unroll
        for (int j = 0; j < 8; ++j) {
          acc[i][j] += a[i].x * b[j].x;
          acc[i][j] += a[i].y * b[j].y;
          acc[i][j] += a[i].z * b[j].z;
          acc[i][j] += a[i].w * b[j].w;
        }
    }
    __syncthreads();
  }
#pragma unroll
  for (int i = 0; i < 8; ++i) {
    int m = m0 + ty * 4 + (i < 4 ? i : 64 + i - 4);
#pragma unroll
    for (int j = 0; j < 8; ++j)
      out[m * HH + n0 + tx + 16 * j] = acc[i][j];
  }
}

// ---- one chunk of the h.U^T MFMA work: producers C*16..C*16+16 ------------
// (k-range C*256..+256 = af indices C*8..C*8+8). C and u compile-time =>
// ufrag is constant-indexed (no scratch spill).
template <int C>
__device__ __forceinline__ void proc_chunk(const unsigned long long* hrow,
                                           int q, const s16x8 (&ufrag)[32],
                                           f32x4& a0, f32x4& a1, f32x4& a2,
                                           f32x4& a3) {
#pragma unroll
  for (int u = 0; u < 8; ++u) {
    const int kc = C * 8 + u;
    unsigned long long lo = __hip_atomic_load(
        hrow + kc * 8 + q * 2, __ATOMIC_RELAXED, __HIP_MEMORY_SCOPE_SYSTEM);
    unsigned long long hi = __hip_atomic_load(
        hrow + kc * 8 + q * 2 + 1, __ATOMIC_RELAXED, __HIP_MEMORY_SCOPE_SYSTEM);
    union { unsigned long long w[2]; s16x8 v; } cv;
    cv.w[0] = lo; cv.w[1] = hi;
    if ((u & 3) == 0)
      a0 = __builtin_amdgcn_mfma_f32_16x16x32_bf16(cv.v, ufrag[kc], a0, 0, 0, 0);
    else if ((u & 3) == 1)
      a1 = __builtin_amdgcn_mfma_f32_16x16x32_bf16(cv.v, ufrag[kc], a1, 0, 0, 0);
    else if ((u & 3) == 2)
      a2 = __builtin_amdgcn_mfma_f32_16x16x32_bf16(cv.v, ufrag[kc], a2, 0, 0, 0);
    else
      a3 = __builtin_amdgcn_mfma_f32_16x16x32_bf16(cv.v, ufrag[kc], a3, 0, 0, 0);
  }
}

// ---------------- Phase 2: persistent scan ----------------------------------
// 128 WGs x 64 threads (1 wave). WG = (mg 0..1) x (jg 0..63): owns batches
// mg*16..+16, cols jg*16..+16. The two mg halves are fully independent.
//
// Protocol: producer h stores (sys) -> s_waitcnt vmcnt(0) -> lane0 stores
// flags[jg]=t+1 (plain monotonic). Consumer at step t: poll flags[l] (one
// 64-lane load), ballot(f>=t); process chunk c when bits c*16..+16 all set.
// flag >= t  <=>  producer finished step t-1 entirely (reads AND drained
// writes), so chunk reads of buf[t&1] and our later writes to buf[(t+1)&1]
// are race-free (same invariant as the R3 counter protocol).
__global__ __launch_bounds__(64, 1) void liquid_scan(
    const unsigned short* __restrict__ Ub,   // U bf16 [1024][1024]
    unsigned short* hbuf,                    // bf16 [2][32][1024] (exchange)
    int* arrivals,                           // [2][64] flags, 256 B apart
    float* __restrict__ hf,                  // h_final f32 [32][1024]
    float* __restrict__ states,              // [32][1024][1024]; holds xW at t
    const float* __restrict__ bias,
    const float* __restrict__ tau) {
  const int l = threadIdx.x;
  const int wg = blockIdx.x;
  const int mg = wg >> 6;            // 0..1
  const int jg = wg & 63;            // 0..63
  const int n = l & 15;              // MFMA col
  const int q = l >> 4;              // 0..3
  const int j = jg * 16 + n;         // this lane's output column
  const int arow = mg * 16 + n;      // A-fragment h row

  const unsigned long long deadline =
      __builtin_amdgcn_s_memrealtime() + 100000000ULL;  // +1 s @ 100 MHz

  // B fragments: lane holds B[k=q*8+i][n] = U[j][kc*32 + q*8 + i], 16 B each.
  s16x8 ufrag[32];
#pragma unroll
  for (int kc = 0; kc < 32; ++kc)
    ufrag[kc] = *(const s16x8*)(Ub + (size_t)j * HH + kc * 32 + q * 8);

  const float bj = bias[j];
  const float invt = 1.0f / tau[j];
  int* const myflags = arrivals + mg * 64;   // groups 256 B apart

  // h f32 register-resident: lane owns rows b = mg*16 + q*4 + r, col j.
  float hold[4] = {0.f, 0.f, 0.f, 0.f};
  float xw[4];
#pragma unroll
  for (int r = 0; r < 4; ++r)
    xw[r] = states[((size_t)(mg * 16 + q * 4 + r) * TT + 0) * HH + j];

  bool dead = false;
  for (int t = 0; t < TT; ++t) {
    const unsigned short* hin = hbuf + (size_t)(t & 1) * (BB * HH);
    unsigned short* hout = hbuf + (size_t)((t + 1) & 1) * (BB * HH);

    // prefetch next step's xw EARLY (lane-private; latency hides under the
    // barrier wait).
    const int tn = (t + 1 < TT) ? t + 1 : TT - 1;
    float xwn[4];
#pragma unroll
    for (int r = 0; r < 4; ++r)
      xwn[r] = states[((size_t)(mg * 16 + q * 4 + r) * TT + tn) * HH + j];

    f32x4 a0 = {0.f, 0.f, 0.f, 0.f}, a1 = {0.f, 0.f, 0.f, 0.f};
    f32x4 a2 = {0.f, 0.f, 0.f, 0.f}, a3 = {0.f, 0.f, 0.f, 0.f};

    if (t > 0) {  // t==0: h=0 => h.U^T = 0, skip entirely
      const unsigned long long* hrow =
          (const unsigned long long*)(hin + (size_t)arow * HH);
      int done = 0;
      while (done < 4 && !dead) {
        int f = __hip_atomic_load(&myflags[l], __ATOMIC_RELAXED,
                                  __HIP_MEMORY_SCOPE_SYSTEM);
        unsigned long long m = __ballot(f >= t);
        bool progressed = false;
        while (done < 4 &&
               ((m >> (16 * done)) & 0xffffULL) == 0xffffULL) {
          switch (done) {
            case 0: proc_chunk<0>(hrow, q, ufrag, a0, a1, a2, a3); break;
            case 1: proc_chunk<1>(hrow, q, ufrag, a0, a1, a2, a3); break;
            case 2: proc_chunk<2>(hrow, q, ufrag, a0, a1, a2, a3); break;
            default: proc_chunk<3>(hrow, q, ufrag, a0, a1, a2, a3); break;
          }
          ++done;
          progressed = true;
        }
        if (done < 4 && !progressed) {
          __builtin_amdgcn_s_sleep(1);
          if (__builtin_amdgcn_s_memrealtime() > deadline) dead = true;
        }
      }
      if (dead) break;
      __builtin_amdgcn_sched_barrier(0);
    }
    f32x4 acc = (a0 + a1) + (a2 + a3);

    // epilogue: D[row=q*4+r][col=n] -> batch b = mg*16+q*4+r, col j.
    float hn[4];
#pragma unroll
    for (int r = 0; r < 4; ++r) {
      const int b = mg * 16 + q * 4 + r;
      float pre = xw[r] + acc[r] + bj;
      float act = fast_tanh(pre);
      float hnew = hold[r] + DT * (act - invt * hold[r]);
      hold[r] = hnew;
      hn[r] = hnew;
      __hip_atomic_store(hout + b * HH + j, f2bf(hnew), __ATOMIC_RELAXED,
                         __HIP_MEMORY_SCOPE_SYSTEM);
      xw[r] = xwn[r];
    }

    // publish: drain the h-stores to the coherent point, then lane 0 stores
    // this WG's flag (plain monotonic store -- no RMW serialization).
    asm volatile("s_waitcnt vmcnt(0)" ::: "memory");
    if (l == 0)
      __hip_atomic_store(&myflags[jg], t + 1, __ATOMIC_RELAXED,
                         __HIP_MEMORY_SCOPE_SYSTEM);

    // states stores: lane-private, read by nobody else -> normal cached
    // stores AFTER the flag store (off the cross-WG critical path).
#pragma unroll
    for (int r = 0; r < 4; ++r) {
      const int b = mg * 16 + q * 4 + r;
      states[((size_t)b * TT + t) * HH + j] = hn[r];
    }
  }

  // h_final
#pragma unroll
  for (int r = 0; r < 4; ++r)
    hf[(mg * 16 + q * 4 + r) * HH + j] = hold[r];
}

// ---------------------------------------------------------------------------
extern "C" void kernel_launch(void* const* d_in, const int* in_sizes, int n_in,
                              void* d_out, int out_size, void* d_ws, size_t ws_size,
                              hipStream_t stream) {
  const float* x    = (const float*)d_in[0];
  const float* W    = (const float*)d_in[1];
  const float* U    = (const float*)d_in[2];
  const float* bias = (const float*)d_in[3];
  const float* tau  = (const float*)d_in[4];

  float* out = (float*)d_out;
  float* hf = out;                         // [32][1024] -> h_final
  float* states = out + BB * HH;           // [32][1024][1024]

  unsigned short* Ub = (unsigned short*)d_ws;            // 2 MB
  unsigned short* hbuf = Ub + (size_t)HH * HH;           // 128 KB (2 buffers)
  int* arrivals = (int*)(hbuf + 2 * BB * HH);            // 512 B

  // init exchange buffers + flags (ws is re-poisoned before every call)
  hipMemsetAsync(hbuf, 0,
                 2 * BB * HH * sizeof(unsigned short) + 128 * sizeof(int),
                 stream);

  cvt_u_kernel<<<(HH * HH) / (256 * 4), 256, 0, stream>>>(U, Ub);

  // Phase 1: xW into the states region (overwritten in-place by the scan).
  xw_gemm<<<dim3(HH / 128, (BB * TT) / 128), 256, 0, stream>>>(x, W, states);

  // Phase 2: single persistent kernel; 128 WGs x 1 wave (proven structure).
  liquid_scan<<<128, 64, 0, stream>>>(Ub, hbuf, arrivals, hf, states, bias, tau);
}

// Round 7
// 4247.561 us; speedup vs baseline: 2.2604x; 2.0089x over previous
//
#include <hip/hip_runtime.h>

// LiquidLayer: h_t = h + DT*(-h/tau + tanh(xW_t + h U^T + b)), T=1024 steps.
// Out = [h_final (32x1024) | states (32x1024x1024)] f32.
// Phase 1: xW GEMM (f32, tiled) written in-place into states region.
// Phase 2: ONE persistent kernel, 128 WGs x 1 wave (R3 proven shape; R4's
//          4-wave concentration and R6's chunked consumption both regressed).
//          Cross-WG exchange of bf16 h through the coherent point using
//          sc0+sc1 accesses (bypass L1 + non-coherent per-XCD L2); NO
//          cache-maintenance ops, NO atomic RMW.
//          Barrier = 64-entry per-group flag array: producer lane0 does a
//          plain monotonic sys-store flags[jg]=t+1; consumer lane l polls
//          flags[l] (one 64-lane load) + __all(f>=t), wait-ALL-then-blast.
//          Lean poll (no s_sleep; serializing s_memrealtime watchdog only
//          every 64 misses; 1s deadline => can never hang the container).
//          A-fragments: 32 x asm global_load_dwordx4 sc0 sc1 (16B), all in
//          flight, one vmcnt(0) double-fenced with sched_barrier(0).

#define DT 0.1f
#define BB 32
#define TT 1024
#define II 512
#define HH 1024

typedef __attribute__((ext_vector_type(4))) float f32x4;
typedef __attribute__((ext_vector_type(8))) short s16x8;

__device__ __forceinline__ unsigned short f2bf(float f) {
  unsigned int u = __builtin_bit_cast(unsigned int, f);
  u += 0x7fffu + ((u >> 16) & 1u);  // RNE
  return (unsigned short)(u >> 16);
}

// tanh via HW exp2 + rcp: tanh(x) = 1 - 2/(e^{2x}+1). |err| ~1e-6 << bf16
// h quantization (2e-3). ~8 instr vs ~40 for ocml tanhf.
__device__ __forceinline__ float fast_tanh(float x) {
  float z = __expf(2.0f * x);
  return 1.0f - 2.0f * __builtin_amdgcn_rcpf(z + 1.0f);
}

// ---------------- U f32 -> bf16 (runs every call; ws is re-poisoned) --------
__global__ __launch_bounds__(256) void cvt_u_kernel(const float* __restrict__ U,
                                                    unsigned short* __restrict__ Ub) {
  int i4 = (blockIdx.x * 256 + threadIdx.x) * 4;
  float4 v = *(const float4*)(U + i4);
  ushort4 o;
  o.x = f2bf(v.x); o.y = f2bf(v.y); o.z = f2bf(v.z); o.w = f2bf(v.w);
  *(ushort4*)(Ub + i4) = o;
}

// ---------------- Phase 1: xW[m][n] = sum_k x[m][k] * W[n][k] (f32) ---------
// M=32768, N=1024, K=512. Block tile 128x128, 256 threads, 8x8 per thread.
#define P1_LDK 36  // LDS row stride (words): pad 32->36; even, 16B-aligned rows

__global__ __launch_bounds__(256) void xw_gemm(const float* __restrict__ x,
                                               const float* __restrict__ W,
                                               float* __restrict__ out) {
  __shared__ __align__(16) float Xs[128 * P1_LDK];
  __shared__ __align__(16) float Ws_s[128 * P1_LDK];
  const int tid = threadIdx.x;
  const int m0 = blockIdx.y * 128;
  const int n0 = blockIdx.x * 128;
  const int ty = tid >> 4;       // 0..15
  const int tx = tid & 15;       // 0..15
  const int lrow = tid >> 3;     // loader: 0..31
  const int lf = tid & 7;        // loader: float4 column 0..7

  float acc[8][8];
#pragma unroll
  for (int i = 0; i < 8; ++i)
#pragma unroll
    for (int j = 0; j < 8; ++j) acc[i][j] = 0.0f;

  for (int kk = 0; kk < II; kk += 32) {
#pragma unroll
    for (int p = 0; p < 4; ++p) {
      int r = lrow + 32 * p;
      float4 vx = *(const float4*)&x[(m0 + r) * II + kk + 4 * lf];
      *(float4*)&Xs[r * P1_LDK + 4 * lf] = vx;
      float4 vw = *(const float4*)&W[(n0 + r) * II + kk + 4 * lf];
      *(float4*)&Ws_s[r * P1_LDK + 4 * lf] = vw;
    }
    __syncthreads();
#pragma unroll
    for (int kq = 0; kq < 32; kq += 4) {
      float4 a[8], b[8];
#pragma unroll
      for (int i = 0; i < 4; ++i) {
        a[i]     = *(const float4*)&Xs[(ty * 4 + i) * P1_LDK + kq];
        a[i + 4] = *(const float4*)&Xs[(ty * 4 + i + 64) * P1_LDK + kq];
      }
#pragma unroll
      for (int j = 0; j < 8; ++j)
        b[j] = *(const float4*)&Ws_s[(tx + 16 * j) * P1_LDK + kq];
#pragma unroll
      for (int i = 0; i < 8; ++i)
#pragma unroll
        for (int j = 0; j < 8; ++j) {
          acc[i][j] += a[i].x * b[j].x;
          acc[i][j] += a[i].y * b[j].y;
          acc[i][j] += a[i].z * b[j].z;
          acc[i][j] += a[i].w * b[j].w;
        }
    }
    __syncthreads();
  }
#pragma unroll
  for (int i = 0; i < 8; ++i) {
    int m = m0 + ty * 4 + (i < 4 ? i : 64 + i - 4);
#pragma unroll
    for (int j = 0; j < 8; ++j)
      out[m * HH + n0 + tx + 16 * j] = acc[i][j];
  }
}

// ---------------- Phase 2: persistent scan ----------------------------------
// 128 WGs x 64 threads (1 wave). WG = (mg 0..1) x (jg 0..63): owns batches
// mg*16..+16, cols jg*16..+16. The two mg halves are fully independent
// (disjoint flags / h rows / states rows).
//
// Protocol: producer h stores (sys) -> s_waitcnt vmcnt(0) -> lane0 plain
// monotonic sys-store flags[jg]=t+1. Consumer at step t: poll flags[l],
// __all(f>=t) -> blast all 32 x 16B A-fragment loads (full MLP) -> MFMA.
// flag >= t  <=>  that producer finished step t-1 entirely (reads AND
// drained writes) => reads of buf[t&1] and writes of buf[(t+1)&1] race-free.
__global__ __launch_bounds__(64, 1) void liquid_scan(
    const unsigned short* __restrict__ Ub,   // U bf16 [1024][1024]
    unsigned short* hbuf,                    // bf16 [2][32][1024] (exchange)
    int* arrivals,                           // [2][64] flags, 256 B apart
    float* __restrict__ hf,                  // h_final f32 [32][1024]
    float* __restrict__ states,              // [32][1024][1024]; holds xW at t
    const float* __restrict__ bias,
    const float* __restrict__ tau) {
  const int l = threadIdx.x;
  const int wg = blockIdx.x;
  const int mg = wg >> 6;            // 0..1
  const int jg = wg & 63;            // 0..63
  const int n = l & 15;              // MFMA col
  const int q = l >> 4;              // 0..3
  const int j = jg * 16 + n;         // this lane's output column
  const int arow = mg * 16 + n;      // A-fragment h row

  const unsigned long long deadline =
      __builtin_amdgcn_s_memrealtime() + 100000000ULL;  // +1 s @ 100 MHz

  // B fragments: lane holds B[k=q*8+i][n] = U[j][kc*32 + q*8 + i], 16 B each.
  s16x8 ufrag[32];
#pragma unroll
  for (int kc = 0; kc < 32; ++kc)
    ufrag[kc] = *(const s16x8*)(Ub + (size_t)j * HH + kc * 32 + q * 8);

  const float bj = bias[j];
  const float invt = 1.0f / tau[j];
  int* const myflags = arrivals + mg * 64;   // groups 256 B apart

  // h f32 register-resident: lane owns rows b = mg*16 + q*4 + r, col j.
  float hold[4] = {0.f, 0.f, 0.f, 0.f};
  float xw[4];
#pragma unroll
  for (int r = 0; r < 4; ++r)
    xw[r] = states[((size_t)(mg * 16 + q * 4 + r) * TT + 0) * HH + j];

  bool dead = false;
  for (int t = 0; t < TT; ++t) {
    const unsigned short* hin = hbuf + (size_t)(t & 1) * (BB * HH);
    unsigned short* hout = hbuf + (size_t)((t + 1) & 1) * (BB * HH);

    // prefetch next step's xw EARLY (lane-private; HBM latency hides under
    // the barrier wait).
    const int tn = (t + 1 < TT) ? t + 1 : TT - 1;
    float xwn[4];
#pragma unroll
    for (int r = 0; r < 4; ++r)
      xwn[r] = states[((size_t)(mg * 16 + q * 4 + r) * TT + tn) * HH + j];

    f32x4 a0 = {0.f, 0.f, 0.f, 0.f}, a1 = {0.f, 0.f, 0.f, 0.f};
    f32x4 a2 = {0.f, 0.f, 0.f, 0.f}, a3 = {0.f, 0.f, 0.f, 0.f};

    if (t > 0) {  // t==0: h=0 => h.U^T = 0, skip wait+load+MFMA entirely
      // ---- wait-all: lean poll, one 64-lane flag load per iteration ----
      int iter = 0;
      for (;;) {
        int f = __hip_atomic_load(&myflags[l], __ATOMIC_RELAXED,
                                  __HIP_MEMORY_SCOPE_SYSTEM);
        if (__all(f >= t)) break;
        if (((++iter) & 63) == 0 &&
            __builtin_amdgcn_s_memrealtime() > deadline) { dead = true; break; }
      }
      if (dead) break;
      __builtin_amdgcn_sched_barrier(0);

      // ---- blast: 32 x 16B sc0/sc1 loads, all in flight, then one wait ----
      // lane holds A[m=l&15][k=q*8+i] = h[arow][kc*32 + q*8 + i].
      const unsigned short* hbase = hin + (size_t)arow * HH + q * 8;
      s16x8 af[32];
#pragma unroll
      for (int kc = 0; kc < 32; ++kc)
        asm volatile("global_load_dwordx4 %0, %1, off sc0 sc1"
                     : "=v"(af[kc]) : "v"(hbase + kc * 32) : "memory");
      __builtin_amdgcn_sched_barrier(0);
      asm volatile("s_waitcnt vmcnt(0)" ::: "memory");
      __builtin_amdgcn_sched_barrier(0);

      // 4 accumulator chains to break MFMA latency serialization.
#pragma unroll
      for (int kc = 0; kc < 32; kc += 4) {
        a0 = __builtin_amdgcn_mfma_f32_16x16x32_bf16(af[kc + 0], ufrag[kc + 0], a0, 0, 0, 0);
        a1 = __builtin_amdgcn_mfma_f32_16x16x32_bf16(af[kc + 1], ufrag[kc + 1], a1, 0, 0, 0);
        a2 = __builtin_amdgcn_mfma_f32_16x16x32_bf16(af[kc + 2], ufrag[kc + 2], a2, 0, 0, 0);
        a3 = __builtin_amdgcn_mfma_f32_16x16x32_bf16(af[kc + 3], ufrag[kc + 3], a3, 0, 0, 0);
      }
    }
    f32x4 acc = (a0 + a1) + (a2 + a3);

    // epilogue: D[row=q*4+r][col=n] -> batch b = mg*16+q*4+r, col j.
    float hn[4];
#pragma unroll
    for (int r = 0; r < 4; ++r) {
      const int b = mg * 16 + q * 4 + r;
      float pre = xw[r] + acc[r] + bj;
      float act = fast_tanh(pre);
      float hnew = hold[r] + DT * (act - invt * hold[r]);
      hold[r] = hnew;
      hn[r] = hnew;
      __hip_atomic_store(hout + b * HH + j, f2bf(hnew), __ATOMIC_RELAXED,
                         __HIP_MEMORY_SCOPE_SYSTEM);
      xw[r] = xwn[r];
    }

    // publish: drain the h-stores to the coherent point, then lane 0 stores
    // this WG's flag (plain monotonic store -- no RMW serialization).
    asm volatile("s_waitcnt vmcnt(0)" ::: "memory");
    if (l == 0)
      __hip_atomic_store(&myflags[jg], t + 1, __ATOMIC_RELAXED,
                         __HIP_MEMORY_SCOPE_SYSTEM);

    // states stores: lane-private, read by nobody else -> normal cached
    // stores AFTER the flag store (off the cross-WG critical path).
#pragma unroll
    for (int r = 0; r < 4; ++r) {
      const int b = mg * 16 + q * 4 + r;
      states[((size_t)b * TT + t) * HH + j] = hn[r];
    }
  }

  // h_final
#pragma unroll
  for (int r = 0; r < 4; ++r)
    hf[(mg * 16 + q * 4 + r) * HH + j] = hold[r];
}

// ---------------------------------------------------------------------------
extern "C" void kernel_launch(void* const* d_in, const int* in_sizes, int n_in,
                              void* d_out, int out_size, void* d_ws, size_t ws_size,
                              hipStream_t stream) {
  const float* x    = (const float*)d_in[0];
  const float* W    = (const float*)d_in[1];
  const float* U    = (const float*)d_in[2];
  const float* bias = (const float*)d_in[3];
  const float* tau  = (const float*)d_in[4];

  float* out = (float*)d_out;
  float* hf = out;                         // [32][1024] -> h_final
  float* states = out + BB * HH;           // [32][1024][1024]

  unsigned short* Ub = (unsigned short*)d_ws;            // 2 MB
  unsigned short* hbuf = Ub + (size_t)HH * HH;           // 128 KB (2 buffers)
  int* arrivals = (int*)(hbuf + 2 * BB * HH);            // 512 B

  // init exchange buffers + flags (ws is re-poisoned before every call)
  hipMemsetAsync(hbuf, 0,
                 2 * BB * HH * sizeof(unsigned short) + 128 * sizeof(int),
                 stream);

  cvt_u_kernel<<<(HH * HH) / (256 * 4), 256, 0, stream>>>(U, Ub);

  // Phase 1: xW into the states region (overwritten in-place by the scan).
  xw_gemm<<<dim3(HH / 128, (BB * TT) / 128), 256, 0, stream>>>(x, W, states);

  // Phase 2: single persistent kernel; 128 WGs x 1 wave (proven structure).
  liquid_scan<<<128, 64, 0, stream>>>(Ub, hbuf, arrivals, hf, states, bias, tau);
}